// Round 15
// baseline (102.628 us; speedup 1.0000x reference)
//
#include <hip/hip_runtime.h>
#include <hip/hip_bf16.h>
#include <math.h>

#define HH 512
#define PP 256
#define LSEQ 4096
#define BB 8
#define MTOT (BB*LSEQ)   // 32768
#define N2P 512          // 2*P

typedef __attribute__((ext_vector_type(8))) short bf16x8;
typedef __attribute__((ext_vector_type(4))) float f32x4;
typedef __attribute__((ext_vector_type(8))) unsigned short u16x8;
typedef __attribute__((ext_vector_type(4))) unsigned short u16x4;

// XOR-swizzle on byte bits 4-6 of each 128B LDS row
#define SWZ(row) (((((row) & 7) ^ (((row) >> 3) & 7)) << 4))

__device__ inline unsigned short f2b(float x) {
    return __builtin_bit_cast(unsigned short, __float2bfloat16(x));
}
__device__ inline float b2f(unsigned short h) {
    union { unsigned int u; float f; } v; v.u = ((unsigned int)h) << 16;
    return v.f;
}

// async global->LDS, 16B per lane; dest = wave-uniform base + lane*16
#define GLOAD16(gp, lp) __builtin_amdgcn_global_load_lds( \
    (const __attribute__((address_space(1))) unsigned int*)(gp), \
    (__attribute__((address_space(3))) unsigned int*)(lp), 16, 0, 0)

// swizzled-panel byte offset for element (row r, k); panels [r>>7][k>>6] of
// 128x64 bf16 = 16KB, interior bytes = exact LDS tile image
__device__ inline size_t panel_off(int r, int k) {
    int nblk = r >> 7, rl = r & 127;
    int kblk = k >> 6, kl = k & 63;
    int c = kl >> 3, j = kl & 7;
    return (size_t)(nblk * 8 + kblk) * 16384 + rl * 128 + ((c * 16) ^ SWZ(rl)) + j * 2;
}

// ---------- prep: W1 panels (r = p re | P+p im over h), lambda_bar ----------
__global__ void prep_w1_k(const float* __restrict__ lre, const float* __restrict__ lim,
                          const float* __restrict__ logd,
                          const float* __restrict__ Bre, const float* __restrict__ Bim,
                          char* __restrict__ W1s, float2* __restrict__ lamb) {
    int idx = blockIdx.x * 256 + threadIdx.x;   // over P*H
    if (idx >= PP * HH) return;
    int p = idx >> 9;
    int h = idx & (HH - 1);
    float delta = expf(logd[p]);
    float lr = lre[p], li = lim[p];
    float er = expf(lr * delta);
    float th = li * delta;
    float lbr = er * cosf(th), lbi = er * sinf(th);
    if (h == 0) lamb[p] = make_float2(lbr, lbi);
    float a = lbr - 1.0f, b = lbi;
    float n2 = lr * lr + li * li;
    float gr = (a * lr + b * li) / n2;
    float gi = (b * lr - a * li) / n2;
    float br = Bre[idx], bi = Bim[idx];
    *(unsigned short*)(W1s + panel_off(p, h))      = f2b(gr * br - gi * bi);
    *(unsigned short*)(W1s + panel_off(PP + p, h)) = f2b(gr * bi + gi * br);
}

// ---------- prep: W2 panels over (h, k): k<P -> 2*C_re[h][k]; else -2*C_im ----------
__global__ void prep_w2_k(const float* __restrict__ Cre, const float* __restrict__ Cim,
                          char* __restrict__ W2s) {
    int idx = blockIdx.x * 256 + threadIdx.x;   // over H*2P
    if (idx >= HH * N2P) return;
    int h = idx >> 9;
    int k = idx & 511;
    float v = (k < PP) ? 2.0f * Cre[(size_t)h * PP + k]
                       : -2.0f * Cim[(size_t)h * PP + (k - PP)];
    *(unsigned short*)(W2s + panel_off(h, k)) = f2b(v);
}

// 8-wave MFMA tile compute: 128x128 block, per-wave 64x32, waves 2(m) x 4(n)
#define TILE_COMPUTE(ABUF, BBUF) { \
    bf16x8 af[4][2], bfv[2][2]; \
    _Pragma("unroll") for (int f = 0; f < 4; ++f) { \
      int ar = wm + f * 16 + (lane & 15); \
      _Pragma("unroll") for (int kk = 0; kk < 2; ++kk) \
        af[f][kk] = *(const bf16x8*)((ABUF) + ar * 128 + ((kk * 64 + (lane >> 4) * 16) ^ SWZ(ar))); } \
    _Pragma("unroll") for (int g = 0; g < 2; ++g) { \
      int br = wn + g * 16 + (lane & 15); \
      _Pragma("unroll") for (int kk = 0; kk < 2; ++kk) \
        bfv[g][kk] = *(const bf16x8*)((BBUF) + br * 128 + ((kk * 64 + (lane >> 4) * 16) ^ SWZ(br))); } \
    _Pragma("unroll") for (int f = 0; f < 4; ++f) \
      _Pragma("unroll") for (int g = 0; g < 2; ++g) \
        _Pragma("unroll") for (int kk = 0; kk < 2; ++kk) \
          acc[f][g] = __builtin_amdgcn_mfma_f32_16x16x32_bf16(af[f][kk], bfv[g][kk], acc[f][g], 0, 0, 0); }

// ---------- GEMM1 (persistent-2): T1[r][m] = sum_h u[m][h] * W1[r][h] ----------
// r8 internals (reg-staged fp32 A depth-2, B panel DMA, counted vmcnt) fused
// into a seamless 16-iteration loop over 2 m-tiles; C-write of tile 0 overlaps
// the in-flight staging of tile 1.
__global__ __launch_bounds__(512, 4) void gemm1_k(const float* __restrict__ u,
                                                  const char* __restrict__ W1s,
                                                  unsigned short* __restrict__ T1) {
    __shared__ char smem[65536];
    const int tid = threadIdx.x, wave = tid >> 6, lane = tid & 63;
    const int swz = (blockIdx.x & 7) * 64 + (blockIdx.x >> 3);    // 512 blocks, bijective
    const int m0 = (swz >> 2) * 256;                              // 2 m-tiles per block
    const int nblk = swz & 3, n0 = nblk * 128;
    const int wm = (wave >> 2) * 64, wn = (wave & 3) * 32;
    const int arow = tid >> 2, acol = tid & 3;

    float4 av0[4], av1[4];    // two named reg sets (static indexing only)
    f32x4 acc[4][2] = {};

// IT in [0,16): m-tile = IT>>3, K-step = IT&7
#define G1_A_LOAD(SET, IT) { \
    const float* src = &u[(size_t)(m0 + ((IT) >> 3) * 128 + arow) * HH + ((IT) & 7) * 64 + acol * 16]; \
    SET[0] = *(const float4*)src;       SET[1] = *(const float4*)(src + 4); \
    SET[2] = *(const float4*)(src + 8); SET[3] = *(const float4*)(src + 12); }

#define G1_A_WRITE(SET, ABUF) { \
    bf16x8 p0, p1; \
    p0[0] = (short)f2b(SET[0].x); p0[1] = (short)f2b(SET[0].y); \
    p0[2] = (short)f2b(SET[0].z); p0[3] = (short)f2b(SET[0].w); \
    p0[4] = (short)f2b(SET[1].x); p0[5] = (short)f2b(SET[1].y); \
    p0[6] = (short)f2b(SET[1].z); p0[7] = (short)f2b(SET[1].w); \
    p1[0] = (short)f2b(SET[2].x); p1[1] = (short)f2b(SET[2].y); \
    p1[2] = (short)f2b(SET[2].z); p1[3] = (short)f2b(SET[2].w); \
    p1[4] = (short)f2b(SET[3].x); p1[5] = (short)f2b(SET[3].y); \
    p1[6] = (short)f2b(SET[3].z); p1[7] = (short)f2b(SET[3].w); \
    *(bf16x8*)((ABUF) + arow * 128 + ((acol * 32)      ^ SWZ(arow))) = p0; \
    *(bf16x8*)((ABUF) + arow * 128 + ((acol * 32 + 16) ^ SWZ(arow))) = p1; }

#define G1_B_GLOAD(IT, BBUF) { \
    const char* pan = W1s + (size_t)(nblk * 8 + ((IT) & 7)) * 16384 + tid * 16; \
    GLOAD16(pan, (BBUF) + tid * 16); \
    GLOAD16(pan + 8192, (BBUF) + tid * 16 + 8192); }

// transposed C-write for m-tile MT from acc
#define G1_C_WRITE(MT) { \
    _Pragma("unroll") for (int f = 0; f < 4; ++f) { \
      _Pragma("unroll") for (int g = 0; g < 2; ++g) { \
        int r = n0 + wn + g * 16 + (lane & 15); \
        int m = m0 + (MT) * 128 + wm + f * 16 + ((lane >> 4) << 2); \
        u16x4 pk; \
        pk[0] = f2b(acc[f][g][0]); pk[1] = f2b(acc[f][g][1]); \
        pk[2] = f2b(acc[f][g][2]); pk[3] = f2b(acc[f][g][3]); \
        *(u16x4*)&T1[(size_t)r * MTOT + m] = pk; } } }

    char* A0 = smem;          char* B0 = smem + 16384;
    char* A1 = smem + 32768;  char* B1 = smem + 49152;

    // prologue: it0 -> av1, it1 -> av0; B(0) DMA; write it0 to LDS
    G1_A_LOAD(av1, 0);
    G1_B_GLOAD(0, B0);
    G1_A_LOAD(av0, 1);
    asm volatile("s_waitcnt vmcnt(4)" ::: "memory");   // drain A(0)+B(0), keep A(1)
    G1_A_WRITE(av1, A0);
    __syncthreads();

    #pragma unroll
    for (int it = 0; it < 16; ++it) {
        char* Ac = (it & 1) ? A1 : A0; char* Bc = (it & 1) ? B1 : B0;
        char* An = (it & 1) ? A0 : A1; char* Bn = (it & 1) ? B0 : B1;
        if (it < 15) G1_B_GLOAD(it + 1, Bn);                     // 2 vm (L2-hot)
        if (it < 14) {                                           // A tile it+2 (4 vm)
            if ((it & 1) == 0) { G1_A_LOAD(av1, it + 2); }
            else               { G1_A_LOAD(av0, it + 2); }
        }
        TILE_COMPUTE(Ac, Bc);
        if (it < 15) {                                           // write tile it+1
            if ((it & 1) == 0) { G1_A_WRITE(av0, An); }
            else               { G1_A_WRITE(av1, An); }
        }
        if (it == 7) {
            // m-tile 0 done: write it out while tile-1 stage loads are in flight
            G1_C_WRITE(0);
            #pragma unroll
            for (int f = 0; f < 4; ++f)
                #pragma unroll
                for (int g = 0; g < 2; ++g) acc[f][g] = (f32x4){0.f, 0.f, 0.f, 0.f};
            // drain only B(8) (oldest 2); leave A(9) + the 8 C-stores in flight
            asm volatile("s_waitcnt vmcnt(12)" ::: "memory");
        } else if (it < 14) {
            asm volatile("s_waitcnt vmcnt(4)" ::: "memory");
        } else if (it == 14) {
            asm volatile("s_waitcnt vmcnt(0)" ::: "memory");
        }
        if (it < 15) __syncthreads();
    }
    // final epilogue: m-tile 1
    G1_C_WRITE(1);
}

// ---------- GEMM2 (round-8 exact): y[m][h] = sum_k Xs[k][m] * W2[h][k] + D*u ----------
__global__ __launch_bounds__(512, 4) void gemm2_k(const unsigned short* __restrict__ Xs,
                                                  const char* __restrict__ W2s,
                                                  float* __restrict__ y,
                                                  const float* __restrict__ u,
                                                  const float* __restrict__ D) {
    __shared__ char smem[65536];
    const int tid = threadIdx.x, wave = tid >> 6, lane = tid & 63;
    const int swz = (blockIdx.x & 7) * 128 + (blockIdx.x >> 3);
    const int m0 = (swz >> 2) * 128;
    const int nblk = swz & 3, n0 = nblk * 128;
    const int wm = (wave >> 2) * 64, wn = (wave & 3) * 32;
    const int kr = tid >> 5;        // 0..15, 4 k-rows each
    const int mc4 = tid & 31;       // 4-m chunk

    u16x4 xv0[4], xv1[4];
    f32x4 acc[4][2] = {};

#define G2_A_LOAD(SET, K0) { \
    _Pragma("unroll") for (int kk = 0; kk < 4; ++kk) \
        SET[kk] = *(const u16x4*)&Xs[(size_t)((K0) + kr * 4 + kk) * MTOT + m0 + mc4 * 4]; }

#define G2_A_WRITE(SET, ABUF) { \
    _Pragma("unroll") for (int j = 0; j < 4; ++j) { \
        int m = mc4 * 4 + j; \
        u16x4 o; o[0] = SET[0][j]; o[1] = SET[1][j]; o[2] = SET[2][j]; o[3] = SET[3][j]; \
        *(u16x4*)((ABUF) + m * 128 + ((kr * 8) ^ SWZ(m))) = o; } }

#define G2_B_GLOAD(K0, BBUF) { \
    const char* pan = W2s + (size_t)(nblk * 8 + ((K0) >> 6)) * 16384 + tid * 16; \
    GLOAD16(pan, (BBUF) + tid * 16); \
    GLOAD16(pan + 8192, (BBUF) + tid * 16 + 8192); }

    char* A0 = smem;          char* B0 = smem + 16384;
    char* A1 = smem + 32768;  char* B1 = smem + 49152;

    G2_A_LOAD(xv1, 0);
    G2_B_GLOAD(0, B0);
    G2_A_LOAD(xv0, 64);
    asm volatile("s_waitcnt vmcnt(4)" ::: "memory");
    G2_A_WRITE(xv1, A0);
    __syncthreads();

    #pragma unroll
    for (int t = 0; t < 8; ++t) {
        char* Ac = (t & 1) ? A1 : A0; char* Bc = (t & 1) ? B1 : B0;
        char* An = (t & 1) ? A0 : A1; char* Bn = (t & 1) ? B0 : B1;
        if (t < 7) G2_B_GLOAD((t + 1) * 64, Bn);
        if (t < 6) {
            if ((t & 1) == 0) { G2_A_LOAD(xv1, (t + 2) * 64); }
            else              { G2_A_LOAD(xv0, (t + 2) * 64); }
        }
        TILE_COMPUTE(Ac, Bc);
        if (t < 7) {
            if ((t & 1) == 0) { G2_A_WRITE(xv0, An); }
            else              { G2_A_WRITE(xv1, An); }
        }
        if (t < 6)       { asm volatile("s_waitcnt vmcnt(4)" ::: "memory"); }
        else if (t == 6) { asm volatile("s_waitcnt vmcnt(0)" ::: "memory"); }
        __syncthreads();
    }

    // epilogue: fragments -> LDS [m][h] per wave (64x32 fp32 = 8KB), then
    // coalesced row stores (+ D*u)
    float* epi = (float*)smem;
    float* myepi = epi + wave * 2048;
    #pragma unroll
    for (int f = 0; f < 4; ++f) {
        #pragma unroll
        for (int g = 0; g < 2; ++g) {
            int ml = f * 16 + ((lane >> 4) << 2);
            int hl = g * 16 + (lane & 15);
            #pragma unroll
            for (int i = 0; i < 4; ++i)
                myepi[(ml + i) * 32 + hl] = acc[f][g][i];
        }
    }
    __syncthreads();

    #pragma unroll
    for (int it = 0; it < 8; ++it) {
        int idx = it * 512 + tid;          // 0..4095: row ml 0..127, chunk c 0..31
        int ml = idx >> 5, c = idx & 31;
        int w = ((ml >> 6) << 2) + (c >> 3);
        const float4 v = *(const float4*)(epi + w * 2048 + (ml & 63) * 32 + (c & 7) * 4);
        int grow = m0 + ml, gcol = n0 + c * 4;
        const float4 uv = *(const float4*)&u[(size_t)grow * HH + gcol];
        const float4 dv = *(const float4*)&D[gcol];
        float4 o = make_float4(v.x + dv.x * uv.x, v.y + dv.y * uv.y,
                               v.z + dv.z * uv.z, v.w + dv.w * uv.w);
        *(float4*)&y[(size_t)grow * HH + gcol] = o;
    }
}

// ---------- coalesced chunked complex scan (bf16 in/out, fp32 internal) ----------
__global__ __launch_bounds__(256) void scan_k(const unsigned short* __restrict__ T1,
                                              unsigned short* __restrict__ Xs,
                                              const float2* __restrict__ lamb) {
    const int b = blockIdx.x >> 8;
    const int p = blockIdx.x & 255;
    const int t = threadIdx.x;
    const float2 L = lamb[p];

    const size_t baseRe = (size_t)p * MTOT + (size_t)b * LSEQ + t * 16;
    const size_t baseIm = (size_t)(PP + p) * MTOT + (size_t)b * LSEQ + t * 16;

    u16x8 r0 = *(const u16x8*)&T1[baseRe];
    u16x8 r1 = *(const u16x8*)&T1[baseRe + 8];
    u16x8 i0 = *(const u16x8*)&T1[baseIm];
    u16x8 i1 = *(const u16x8*)&T1[baseIm + 8];

    float re[16], im[16];
    #pragma unroll
    for (int j = 0; j < 8; ++j) {
        re[j] = b2f(r0[j]); re[8 + j] = b2f(r1[j]);
        im[j] = b2f(i0[j]); im[8 + j] = b2f(i1[j]);
    }

    float sr = 0.f, si = 0.f;
    #pragma unroll
    for (int j = 0; j < 16; ++j) {
        float nsr = L.x * sr - L.y * si + re[j];
        si = L.x * si + L.y * sr + im[j];
        sr = nsr;
    }

    __shared__ float cr[256], ci[256];
    cr[t] = sr; ci[t] = si;
    __syncthreads();

    float wr = L.x, wi = L.y;
    #pragma unroll
    for (int q = 0; q < 4; ++q) { float nr = wr * wr - wi * wi; wi = 2.f * wr * wi; wr = nr; }

    for (int off = 1; off < 256; off <<= 1) {
        float pr = 0.f, pi = 0.f;
        const bool has = (t >= off);
        if (has) { pr = cr[t - off]; pi = ci[t - off]; }
        __syncthreads();
        if (has) {
            sr += wr * pr - wi * pi;
            si += wr * pi + wi * pr;
            cr[t] = sr; ci[t] = si;
        }
        __syncthreads();
        float nr = wr * wr - wi * wi; wi = 2.f * wr * wi; wr = nr;
    }

    float xr = 0.f, xi = 0.f;
    if (t > 0) { xr = cr[t - 1]; xi = ci[t - 1]; }

    u16x8 o0, o1, o2, o3;
    #pragma unroll
    for (int j = 0; j < 16; ++j) {
        float nr = L.x * xr - L.y * xi + re[j];
        xi = L.x * xi + L.y * xr + im[j];
        xr = nr;
        if (j < 8) { o0[j] = f2b(xr); o2[j] = f2b(xi); }
        else       { o1[j - 8] = f2b(xr); o3[j - 8] = f2b(xi); }
    }
    *(u16x8*)&Xs[baseRe]     = o0;
    *(u16x8*)&Xs[baseRe + 8] = o1;
    *(u16x8*)&Xs[baseIm]     = o2;
    *(u16x8*)&Xs[baseIm + 8] = o3;
}

// ---------- launch ----------

extern "C" void kernel_launch(void* const* d_in, const int* in_sizes, int n_in,
                              void* d_out, int out_size, void* d_ws, size_t ws_size,
                              hipStream_t stream) {
    const float* u    = (const float*)d_in[0];
    const float* lre  = (const float*)d_in[1];
    const float* lim  = (const float*)d_in[2];
    const float* Bre  = (const float*)d_in[3];
    const float* Bim  = (const float*)d_in[4];
    const float* Cre  = (const float*)d_in[5];
    const float* Cim  = (const float*)d_in[6];
    const float* Dv   = (const float*)d_in[7];
    const float* logd = (const float*)d_in[8];
    float* out = (float*)d_out;

    char* ws = (char*)d_ws;
    char*           W1s  = ws;                                      // 512 KB (panel images)
    char*           W2s  = ws + (512 << 10);                        // 512 KB
    float2*         lamb = (float2*)(ws + (1 << 20));               // 2 KB
    unsigned short* Xs   = (unsigned short*)(ws + (1 << 20) + 4096);// 32 MB

    unsigned short* T1 = (unsigned short*)d_out;  // 32 MB bf16, overwritten by y later

    prep_w1_k<<<(PP * HH) / 256, 256, 0, stream>>>(lre, lim, logd, Bre, Bim, W1s, lamb);
    prep_w2_k<<<(HH * N2P) / 256, 256, 0, stream>>>(Cre, Cim, W2s);

    // GEMM1 (persistent-2 m-tiles, 512 blocks): u x W1 panels -> T1[r][m] bf16
    gemm1_k<<<512, 512, 0, stream>>>(u, W1s, T1);
    // scan: T1 -> Xs (same transposed layout, bf16)
    scan_k<<<BB * PP, 256, 0, stream>>>(T1, Xs, lamb);
    // GEMM2 (round-8 exact): Xs x W2 panels -> y fp32 (+ D*u epilogue)
    gemm2_k<<<1024, 512, 0, stream>>>(Xs, W2s, out, u, Dv);
}

// Round 16
// 97.413 us; speedup vs baseline: 1.0535x; 1.0535x over previous
//
#include <hip/hip_runtime.h>
#include <hip/hip_bf16.h>
#include <math.h>

#define HH 512
#define PP 256
#define LSEQ 4096
#define BB 8
#define MTOT (BB*LSEQ)   // 32768
#define N2P 512          // 2*P

typedef __attribute__((ext_vector_type(8))) short bf16x8;
typedef __attribute__((ext_vector_type(4))) float f32x4;
typedef __attribute__((ext_vector_type(8))) unsigned short u16x8;
typedef __attribute__((ext_vector_type(4))) unsigned short u16x4;

// XOR-swizzle on byte bits 4-6 of each 128B LDS row
#define SWZ(row) (((((row) & 7) ^ (((row) >> 3) & 7)) << 4))

__device__ inline unsigned short f2b(float x) {
    return __builtin_bit_cast(unsigned short, __float2bfloat16(x));
}
__device__ inline float b2f(unsigned short h) {
    union { unsigned int u; float f; } v; v.u = ((unsigned int)h) << 16;
    return v.f;
}

// async global->LDS, 16B per lane; dest = wave-uniform base + lane*16
#define GLOAD16(gp, lp) __builtin_amdgcn_global_load_lds( \
    (const __attribute__((address_space(1))) unsigned int*)(gp), \
    (__attribute__((address_space(3))) unsigned int*)(lp), 16, 0, 0)

// swizzled-panel byte offset for element (row r, k); panels [r>>7][k>>6] of
// 128x64 bf16 = 16KB, interior bytes = exact LDS tile image
__device__ inline size_t panel_off(int r, int k) {
    int nblk = r >> 7, rl = r & 127;
    int kblk = k >> 6, kl = k & 63;
    int c = kl >> 3, j = kl & 7;
    return (size_t)(nblk * 8 + kblk) * 16384 + rl * 128 + ((c * 16) ^ SWZ(rl)) + j * 2;
}

// ---------- prep: W1 panels (r = p re | P+p im over h), lambda_bar ----------
__global__ void prep_w1_k(const float* __restrict__ lre, const float* __restrict__ lim,
                          const float* __restrict__ logd,
                          const float* __restrict__ Bre, const float* __restrict__ Bim,
                          char* __restrict__ W1s, float2* __restrict__ lamb) {
    int idx = blockIdx.x * 256 + threadIdx.x;   // over P*H
    if (idx >= PP * HH) return;
    int p = idx >> 9;
    int h = idx & (HH - 1);
    float delta = expf(logd[p]);
    float lr = lre[p], li = lim[p];
    float er = expf(lr * delta);
    float th = li * delta;
    float lbr = er * cosf(th), lbi = er * sinf(th);
    if (h == 0) lamb[p] = make_float2(lbr, lbi);
    float a = lbr - 1.0f, b = lbi;
    float n2 = lr * lr + li * li;
    float gr = (a * lr + b * li) / n2;
    float gi = (b * lr - a * li) / n2;
    float br = Bre[idx], bi = Bim[idx];
    *(unsigned short*)(W1s + panel_off(p, h))      = f2b(gr * br - gi * bi);
    *(unsigned short*)(W1s + panel_off(PP + p, h)) = f2b(gr * bi + gi * br);
}

// ---------- prep: W2 panels over (h, k): k<P -> 2*C_re[h][k]; else -2*C_im ----------
__global__ void prep_w2_k(const float* __restrict__ Cre, const float* __restrict__ Cim,
                          char* __restrict__ W2s) {
    int idx = blockIdx.x * 256 + threadIdx.x;   // over H*2P
    if (idx >= HH * N2P) return;
    int h = idx >> 9;
    int k = idx & 511;
    float v = (k < PP) ? 2.0f * Cre[(size_t)h * PP + k]
                       : -2.0f * Cim[(size_t)h * PP + (k - PP)];
    *(unsigned short*)(W2s + panel_off(h, k)) = f2b(v);
}

// 8-wave MFMA tile compute: 128x128 block, per-wave 64x32, waves 2(m) x 4(n)
#define TILE_COMPUTE(ABUF, BBUF) { \
    bf16x8 af[4][2], bfv[2][2]; \
    _Pragma("unroll") for (int f = 0; f < 4; ++f) { \
      int ar = wm + f * 16 + (lane & 15); \
      _Pragma("unroll") for (int kk = 0; kk < 2; ++kk) \
        af[f][kk] = *(const bf16x8*)((ABUF) + ar * 128 + ((kk * 64 + (lane >> 4) * 16) ^ SWZ(ar))); } \
    _Pragma("unroll") for (int g = 0; g < 2; ++g) { \
      int br = wn + g * 16 + (lane & 15); \
      _Pragma("unroll") for (int kk = 0; kk < 2; ++kk) \
        bfv[g][kk] = *(const bf16x8*)((BBUF) + br * 128 + ((kk * 64 + (lane >> 4) * 16) ^ SWZ(br))); } \
    _Pragma("unroll") for (int f = 0; f < 4; ++f) \
      _Pragma("unroll") for (int g = 0; g < 2; ++g) \
        _Pragma("unroll") for (int kk = 0; kk < 2; ++kk) \
          acc[f][g] = __builtin_amdgcn_mfma_f32_16x16x32_bf16(af[f][kk], bfv[g][kk], acc[f][g], 0, 0, 0); }

// ---------- GEMM1: T1[r][m] = sum_h u[m][h] * W1[r][h]  (bf16 MFMA) ----------
// depth-2 pipelined: A regs loaded 2 tiles ahead, LDS written 1 tile ahead,
// counted vmcnt(4) leaves A(t+2)'s 4 loads in flight (never drains to 0 mid-loop)
__global__ __launch_bounds__(512, 4) void gemm1_k(const float* __restrict__ u,
                                                  const char* __restrict__ W1s,
                                                  unsigned short* __restrict__ T1) {
    __shared__ char smem[65536];
    const int tid = threadIdx.x, wave = tid >> 6, lane = tid & 63;
    const int swz = (blockIdx.x & 7) * 128 + (blockIdx.x >> 3);   // XCD-chunked, bijective
    const int m0 = (swz >> 2) * 128;
    const int nblk = swz & 3, n0 = nblk * 128;
    const int wm = (wave >> 2) * 64, wn = (wave & 3) * 32;
    const int arow = tid >> 2, acol = tid & 3;

    float4 av0[4], av1[4];    // two named reg sets (static indexing only)
    f32x4 acc[4][2] = {};

#define G1_A_LOAD(SET, K0) { \
    const float* src = &u[(size_t)(m0 + arow) * HH + (K0) + acol * 16]; \
    SET[0] = *(const float4*)src;       SET[1] = *(const float4*)(src + 4); \
    SET[2] = *(const float4*)(src + 8); SET[3] = *(const float4*)(src + 12); }

#define G1_A_WRITE(SET, ABUF) { \
    bf16x8 p0, p1; \
    p0[0] = (short)f2b(SET[0].x); p0[1] = (short)f2b(SET[0].y); \
    p0[2] = (short)f2b(SET[0].z); p0[3] = (short)f2b(SET[0].w); \
    p0[4] = (short)f2b(SET[1].x); p0[5] = (short)f2b(SET[1].y); \
    p0[6] = (short)f2b(SET[1].z); p0[7] = (short)f2b(SET[1].w); \
    p1[0] = (short)f2b(SET[2].x); p1[1] = (short)f2b(SET[2].y); \
    p1[2] = (short)f2b(SET[2].z); p1[3] = (short)f2b(SET[2].w); \
    p1[4] = (short)f2b(SET[3].x); p1[5] = (short)f2b(SET[3].y); \
    p1[6] = (short)f2b(SET[3].z); p1[7] = (short)f2b(SET[3].w); \
    *(bf16x8*)((ABUF) + arow * 128 + ((acol * 32)      ^ SWZ(arow))) = p0; \
    *(bf16x8*)((ABUF) + arow * 128 + ((acol * 32 + 16) ^ SWZ(arow))) = p1; }

#define G1_B_GLOAD(K0, BBUF) { \
    const char* pan = W1s + (size_t)(nblk * 8 + ((K0) >> 6)) * 16384 + tid * 16; \
    GLOAD16(pan, (BBUF) + tid * 16); \
    GLOAD16(pan + 8192, (BBUF) + tid * 16 + 8192); }

    char* A0 = smem;          char* B0 = smem + 16384;
    char* A1 = smem + 32768;  char* B1 = smem + 49152;

    // prologue: tile0 -> av1, tile1 -> av0; B(0) DMA; write tile0 to LDS
    G1_A_LOAD(av1, 0);
    G1_B_GLOAD(0, B0);
    G1_A_LOAD(av0, 64);
    asm volatile("s_waitcnt vmcnt(4)" ::: "memory");   // drain A(0)+B(0), keep A(1)
    G1_A_WRITE(av1, A0);
    __syncthreads();

    #pragma unroll
    for (int t = 0; t < 8; ++t) {
        char* Ac = (t & 1) ? A1 : A0; char* Bc = (t & 1) ? B1 : B0;
        char* An = (t & 1) ? A0 : A1; char* Bn = (t & 1) ? B0 : B1;
        if (t < 7) G1_B_GLOAD((t + 1) * 64, Bn);                 // 2 vm (L2-hot)
        if (t < 6) {                                             // A tile t+2 (4 vm)
            if ((t & 1) == 0) { G1_A_LOAD(av1, (t + 2) * 64); }
            else              { G1_A_LOAD(av0, (t + 2) * 64); }
        }
        TILE_COMPUTE(Ac, Bc);
        if (t < 7) {                                             // write tile t+1
            if ((t & 1) == 0) { G1_A_WRITE(av0, An); }
            else              { G1_A_WRITE(av1, An); }
        }
        if (t < 6)       { asm volatile("s_waitcnt vmcnt(4)" ::: "memory"); }
        else if (t == 6) { asm volatile("s_waitcnt vmcnt(0)" ::: "memory"); }
        __syncthreads();
    }

    // epilogue: acc -> LDS [r 128][m 128] bf16 (32KB, XOR-swizzled rows),
    // then full-line contiguous T1 row stores
    {
        char* ep = smem;
        #pragma unroll
        for (int f = 0; f < 4; ++f) {
            #pragma unroll
            for (int g = 0; g < 2; ++g) {
                int r = wn + g * 16 + (lane & 15);
                int mb = (wm + f * 16 + ((lane >> 4) << 2)) * 2;
                u16x4 pk;
                pk[0] = f2b(acc[f][g][0]); pk[1] = f2b(acc[f][g][1]);
                pk[2] = f2b(acc[f][g][2]); pk[3] = f2b(acc[f][g][3]);
                *(u16x4*)(ep + r * 256 + (mb ^ ((r & 7) << 4))) = pk;
            }
        }
        __syncthreads();
        #pragma unroll
        for (int it = 0; it < 4; ++it) {
            int r = it * 32 + (tid >> 4);
            int mc = tid & 15;
            u16x8 v = *(const u16x8*)(ep + r * 256 + ((mc * 16) ^ ((r & 7) << 4)));
            *(u16x8*)&T1[(size_t)(n0 + r) * MTOT + m0 + mc * 8] = v;
        }
    }
}

// ---------- GEMM2: y[m][h] = sum_k Xs[k][m] * W2[h][k] + D[h]*u[m][h] ----------
__global__ __launch_bounds__(512, 4) void gemm2_k(const unsigned short* __restrict__ Xs,
                                                  const char* __restrict__ W2s,
                                                  float* __restrict__ y,
                                                  const float* __restrict__ u,
                                                  const float* __restrict__ D) {
    __shared__ char smem[65536];
    const int tid = threadIdx.x, wave = tid >> 6, lane = tid & 63;
    const int swz = (blockIdx.x & 7) * 128 + (blockIdx.x >> 3);
    const int m0 = (swz >> 2) * 128;
    const int nblk = swz & 3, n0 = nblk * 128;
    const int wm = (wave >> 2) * 64, wn = (wave & 3) * 32;
    const int kr = tid >> 5;        // 0..15, 4 k-rows each
    const int mc4 = tid & 31;       // 4-m chunk

    u16x4 xv0[4], xv1[4];
    f32x4 acc[4][2] = {};

#define G2_A_LOAD(SET, K0) { \
    _Pragma("unroll") for (int kk = 0; kk < 4; ++kk) \
        SET[kk] = *(const u16x4*)&Xs[(size_t)((K0) + kr * 4 + kk) * MTOT + m0 + mc4 * 4]; }

#define G2_A_WRITE(SET, ABUF) { \
    _Pragma("unroll") for (int j = 0; j < 4; ++j) { \
        int m = mc4 * 4 + j; \
        u16x4 o; o[0] = SET[0][j]; o[1] = SET[1][j]; o[2] = SET[2][j]; o[3] = SET[3][j]; \
        *(u16x4*)((ABUF) + m * 128 + ((kr * 8) ^ SWZ(m))) = o; } }

#define G2_B_GLOAD(K0, BBUF) { \
    const char* pan = W2s + (size_t)(nblk * 8 + ((K0) >> 6)) * 16384 + tid * 16; \
    GLOAD16(pan, (BBUF) + tid * 16); \
    GLOAD16(pan + 8192, (BBUF) + tid * 16 + 8192); }

    char* A0 = smem;          char* B0 = smem + 16384;
    char* A1 = smem + 32768;  char* B1 = smem + 49152;

    G2_A_LOAD(xv1, 0);
    G2_B_GLOAD(0, B0);
    G2_A_LOAD(xv0, 64);
    asm volatile("s_waitcnt vmcnt(4)" ::: "memory");
    G2_A_WRITE(xv1, A0);
    __syncthreads();

    #pragma unroll
    for (int t = 0; t < 8; ++t) {
        char* Ac = (t & 1) ? A1 : A0; char* Bc = (t & 1) ? B1 : B0;
        char* An = (t & 1) ? A0 : A1; char* Bn = (t & 1) ? B0 : B1;
        if (t < 7) G2_B_GLOAD((t + 1) * 64, Bn);
        if (t < 6) {
            if ((t & 1) == 0) { G2_A_LOAD(xv1, (t + 2) * 64); }
            else              { G2_A_LOAD(xv0, (t + 2) * 64); }
        }
        TILE_COMPUTE(Ac, Bc);
        if (t < 7) {
            if ((t & 1) == 0) { G2_A_WRITE(xv0, An); }
            else              { G2_A_WRITE(xv1, An); }
        }
        if (t < 6)       { asm volatile("s_waitcnt vmcnt(4)" ::: "memory"); }
        else if (t == 6) { asm volatile("s_waitcnt vmcnt(0)" ::: "memory"); }
        __syncthreads();
    }

    // epilogue: fragments -> LDS [m][h] per wave (64x32 fp32 = 8KB), then
    // coalesced row stores (+ D*u)
    float* epi = (float*)smem;
    float* myepi = epi + wave * 2048;
    #pragma unroll
    for (int f = 0; f < 4; ++f) {
        #pragma unroll
        for (int g = 0; g < 2; ++g) {
            int ml = f * 16 + ((lane >> 4) << 2);
            int hl = g * 16 + (lane & 15);
            #pragma unroll
            for (int i = 0; i < 4; ++i)
                myepi[(ml + i) * 32 + hl] = acc[f][g][i];
        }
    }
    __syncthreads();

    #pragma unroll
    for (int it = 0; it < 8; ++it) {
        int idx = it * 512 + tid;          // 0..4095: row ml 0..127, chunk c 0..31
        int ml = idx >> 5, c = idx & 31;
        int w = ((ml >> 6) << 2) + (c >> 3);
        const float4 v = *(const float4*)(epi + w * 2048 + (ml & 63) * 32 + (c & 7) * 4);
        int grow = m0 + ml, gcol = n0 + c * 4;
        const float4 uv = *(const float4*)&u[(size_t)grow * HH + gcol];
        const float4 dv = *(const float4*)&D[gcol];
        float4 o = make_float4(v.x + dv.x * uv.x, v.y + dv.y * uv.y,
                               v.z + dv.z * uv.z, v.w + dv.w * uv.w);
        *(float4*)&y[(size_t)grow * HH + gcol] = o;
    }
}

// ---------- coalesced chunked complex scan (bf16 in/out, fp32 internal) ----------
__global__ __launch_bounds__(256) void scan_k(const unsigned short* __restrict__ T1,
                                              unsigned short* __restrict__ Xs,
                                              const float2* __restrict__ lamb) {
    const int b = blockIdx.x >> 8;
    const int p = blockIdx.x & 255;
    const int t = threadIdx.x;
    const float2 L = lamb[p];

    const size_t baseRe = (size_t)p * MTOT + (size_t)b * LSEQ + t * 16;
    const size_t baseIm = (size_t)(PP + p) * MTOT + (size_t)b * LSEQ + t * 16;

    u16x8 r0 = *(const u16x8*)&T1[baseRe];
    u16x8 r1 = *(const u16x8*)&T1[baseRe + 8];
    u16x8 i0 = *(const u16x8*)&T1[baseIm];
    u16x8 i1 = *(const u16x8*)&T1[baseIm + 8];

    float re[16], im[16];
    #pragma unroll
    for (int j = 0; j < 8; ++j) {
        re[j] = b2f(r0[j]); re[8 + j] = b2f(r1[j]);
        im[j] = b2f(i0[j]); im[8 + j] = b2f(i1[j]);
    }

    float sr = 0.f, si = 0.f;
    #pragma unroll
    for (int j = 0; j < 16; ++j) {
        float nsr = L.x * sr - L.y * si + re[j];
        si = L.x * si + L.y * sr + im[j];
        sr = nsr;
    }

    __shared__ float cr[256], ci[256];
    cr[t] = sr; ci[t] = si;
    __syncthreads();

    float wr = L.x, wi = L.y;
    #pragma unroll
    for (int q = 0; q < 4; ++q) { float nr = wr * wr - wi * wi; wi = 2.f * wr * wi; wr = nr; }

    for (int off = 1; off < 256; off <<= 1) {
        float pr = 0.f, pi = 0.f;
        const bool has = (t >= off);
        if (has) { pr = cr[t - off]; pi = ci[t - off]; }
        __syncthreads();
        if (has) {
            sr += wr * pr - wi * pi;
            si += wr * pi + wi * pr;
            cr[t] = sr; ci[t] = si;
        }
        __syncthreads();
        float nr = wr * wr - wi * wi; wi = 2.f * wr * wi; wr = nr;
    }

    float xr = 0.f, xi = 0.f;
    if (t > 0) { xr = cr[t - 1]; xi = ci[t - 1]; }

    u16x8 o0, o1, o2, o3;
    #pragma unroll
    for (int j = 0; j < 16; ++j) {
        float nr = L.x * xr - L.y * xi + re[j];
        xi = L.x * xi + L.y * xr + im[j];
        xr = nr;
        if (j < 8) { o0[j] = f2b(xr); o2[j] = f2b(xi); }
        else       { o1[j - 8] = f2b(xr); o3[j - 8] = f2b(xi); }
    }
    *(u16x8*)&Xs[baseRe]     = o0;
    *(u16x8*)&Xs[baseRe + 8] = o1;
    *(u16x8*)&Xs[baseIm]     = o2;
    *(u16x8*)&Xs[baseIm + 8] = o3;
}

// ---------- launch ----------

extern "C" void kernel_launch(void* const* d_in, const int* in_sizes, int n_in,
                              void* d_out, int out_size, void* d_ws, size_t ws_size,
                              hipStream_t stream) {
    const float* u    = (const float*)d_in[0];
    const float* lre  = (const float*)d_in[1];
    const float* lim  = (const float*)d_in[2];
    const float* Bre  = (const float*)d_in[3];
    const float* Bim  = (const float*)d_in[4];
    const float* Cre  = (const float*)d_in[5];
    const float* Cim  = (const float*)d_in[6];
    const float* Dv   = (const float*)d_in[7];
    const float* logd = (const float*)d_in[8];
    float* out = (float*)d_out;

    char* ws = (char*)d_ws;
    char*           W1s  = ws;                                      // 512 KB (panel images)
    char*           W2s  = ws + (512 << 10);                        // 512 KB
    float2*         lamb = (float2*)(ws + (1 << 20));               // 2 KB
    unsigned short* Xs   = (unsigned short*)(ws + (1 << 20) + 4096);// 32 MB

    unsigned short* T1 = (unsigned short*)d_out;  // 32 MB bf16, overwritten by y later

    prep_w1_k<<<(PP * HH) / 256, 256, 0, stream>>>(lre, lim, logd, Bre, Bim, W1s, lamb);
    prep_w2_k<<<(HH * N2P) / 256, 256, 0, stream>>>(Cre, Cim, W2s);

    // GEMM1: u (fp32, cvt in-kernel) x W1 panels -> T1[r][m] bf16
    gemm1_k<<<1024, 512, 0, stream>>>(u, W1s, T1);
    // scan: T1 -> Xs (same transposed layout, bf16)
    scan_k<<<BB * PP, 256, 0, stream>>>(T1, Xs, lamb);
    // GEMM2: Xs x W2 panels -> y fp32 (+ D*u epilogue)
    gemm2_k<<<1024, 512, 0, stream>>>(Xs, W2s, out, u, Dv);
}